// Round 1
// baseline (64.925 us; speedup 1.0000x reference)
//
#include <hip/hip_runtime.h>

// Resize [B,D,H,W,C] fp32 by zoom=1.5 per spatial axis, neurite/SynthSeg
// linear-interp convention (edge-clipped). Fixed problem size.
constexpr int B = 2, D = 128, H = 128, W = 128;   // C = 2 handled as float2
constexpr int OD = 192, OH = 192, OW = 192;

__device__ __forceinline__ void axis_interp(int i, int d, int& i0, int& i1, float& w0) {
    // loc = i / 1.5 in fp32 (matches reference: arange/zoom)
    float loc  = (float)i / 1.5f;
    float maxd = (float)(d - 1);
    float cloc = fminf(loc, maxd);            // loc >= 0 always
    float f    = floorf(loc);
    f = fminf(f, maxd);                       // clip(floor(loc), 0, d-1); floor>=0 here
    i0 = (int)f;
    i1 = (i0 + 1 < d) ? (i0 + 1) : (d - 1);
    w0 = (float)i1 - cloc;                    // neurite: weight of lower corner
}

__global__ __launch_bounds__(256)
void resize_trilinear_kernel(const float2* __restrict__ in, float2* __restrict__ out) {
    int idx = blockIdx.x * blockDim.x + threadIdx.x;
    constexpr int total = B * OD * OH * OW;
    if (idx >= total) return;

    int x = idx % OW;
    int t = idx / OW;
    int y = t % OH;
    t /= OH;
    int z = t % OD;
    int b = t / OD;

    int z0, z1, y0, y1, x0, x1;
    float wz0, wy0, wx0;
    axis_interp(z, D, z0, z1, wz0);
    axis_interp(y, H, y0, y1, wy0);
    axis_interp(x, W, x0, x1, wx0);
    float wz1 = 1.f - wz0, wy1 = 1.f - wy0, wx1 = 1.f - wx0;

    const float2* base = in + (size_t)b * D * H * W;
    const float2* pz0y0 = base + ((size_t)z0 * H + y0) * W;
    const float2* pz0y1 = base + ((size_t)z0 * H + y1) * W;
    const float2* pz1y0 = base + ((size_t)z1 * H + y0) * W;
    const float2* pz1y1 = base + ((size_t)z1 * H + y1) * W;

    float2 v000 = pz0y0[x0], v001 = pz0y0[x1];
    float2 v010 = pz0y1[x0], v011 = pz0y1[x1];
    float2 v100 = pz1y0[x0], v101 = pz1y0[x1];
    float2 v110 = pz1y1[x0], v111 = pz1y1[x1];

    float2 r;
    r.x = wz0 * (wy0 * (wx0 * v000.x + wx1 * v001.x) +
                 wy1 * (wx0 * v010.x + wx1 * v011.x)) +
          wz1 * (wy0 * (wx0 * v100.x + wx1 * v101.x) +
                 wy1 * (wx0 * v110.x + wx1 * v111.x));
    r.y = wz0 * (wy0 * (wx0 * v000.y + wx1 * v001.y) +
                 wy1 * (wx0 * v010.y + wx1 * v011.y)) +
          wz1 * (wy0 * (wx0 * v100.y + wx1 * v101.y) +
                 wy1 * (wx0 * v110.y + wx1 * v111.y));

    out[idx] = r;
}

extern "C" void kernel_launch(void* const* d_in, const int* in_sizes, int n_in,
                              void* d_out, int out_size, void* d_ws, size_t ws_size,
                              hipStream_t stream) {
    const float2* in = (const float2*)d_in[0];
    float2* out = (float2*)d_out;
    constexpr int total = B * OD * OH * OW;          // one thread per output spatial pt
    constexpr int block = 256;
    constexpr int grid = (total + block - 1) / block;
    resize_trilinear_kernel<<<grid, block, 0, stream>>>(in, out);
}

// Round 2
// 32.463 us; speedup vs baseline: 2.0000x; 2.0000x over previous
//
#include <hip/hip_runtime.h>

// Resize [B,D,H,W,C=2] fp32, zoom 1.5/axis, neurite linear conv (edge clip).
// Structure: 3 outputs per axis consume 2 inputs with fixed weights
//   out[3k]   = in[2k]
//   out[3k+1] = 1/3 in[2k] + 2/3 in[2k+1]
//   out[3k+2] = 2/3 in[2k+1] + 1/3 in[2k+2]   (index 128 clipped to 127)
// One thread = 3 consecutive x-outputs; block (64,4) = 4 output rows.
constexpr int B = 2, D = 128, H = 128, W = 128;
constexpr int OD = 192, OH = 192, OW = 192;

__device__ __forceinline__ void axis_interp(int i, int d, int& i0, int& i1, float& w0) {
    float loc  = (float)i * (1.0f / 1.5f);
    float maxd = (float)(d - 1);
    float cloc = fminf(loc, maxd);
    float f    = fminf(floorf(loc), maxd);
    i0 = (int)f;
    i1 = (i0 + 1 < d) ? (i0 + 1) : (d - 1);
    w0 = (float)i1 - cloc;     // weight of lower corner
}

__global__ __launch_bounds__(256)
void resize_trilinear3(const float2* __restrict__ in, float2* __restrict__ out) {
    const int t = threadIdx.x;                    // 0..63  -> x-triple index
    const int y = blockIdx.x * 4 + threadIdx.y;   // 0..191 output y
    const int z = blockIdx.y;                     // 0..191 output z
    const int b = blockIdx.z;

    int z0, z1, y0, y1;
    float wz0, wy0;
    axis_interp(z, D, z0, z1, wz0);
    axis_interp(y, H, y0, y1, wy0);
    const float wz1 = 1.f - wz0, wy1 = 1.f - wy0;

    const float2* base = in + (size_t)b * (D * H * W);
    const float2* r00 = base + (z0 * H + y0) * W + 2 * t;
    const float2* r01 = base + (z0 * H + y1) * W + 2 * t;
    const float2* r10 = base + (z1 * H + y0) * W + 2 * t;
    const float2* r11 = base + (z1 * H + y1) * W + 2 * t;
    const int e2 = (t < 63) ? 2 : 1;              // x input 2t+2==128 -> clip

    float2 v00a = r00[0], v00b = r00[1], v00c = r00[e2];
    float2 v01a = r01[0], v01b = r01[1], v01c = r01[e2];
    float2 v10a = r10[0], v10b = r10[1], v10c = r10[e2];
    float2 v11a = r11[0], v11b = r11[1], v11c = r11[e2];

    // bilinear in (z,y) per input x-column
    float c0x = wz0 * (wy0 * v00a.x + wy1 * v01a.x) + wz1 * (wy0 * v10a.x + wy1 * v11a.x);
    float c0y = wz0 * (wy0 * v00a.y + wy1 * v01a.y) + wz1 * (wy0 * v10a.y + wy1 * v11a.y);
    float c1x = wz0 * (wy0 * v00b.x + wy1 * v01b.x) + wz1 * (wy0 * v10b.x + wy1 * v11b.x);
    float c1y = wz0 * (wy0 * v00b.y + wy1 * v01b.y) + wz1 * (wy0 * v10b.y + wy1 * v11b.y);
    float c2x = wz0 * (wy0 * v00c.x + wy1 * v01c.x) + wz1 * (wy0 * v10c.x + wy1 * v11c.x);
    float c2y = wz0 * (wy0 * v00c.y + wy1 * v01c.y) + wz1 * (wy0 * v10c.y + wy1 * v11c.y);

    constexpr float W13 = 1.0f / 3.0f, W23 = 2.0f / 3.0f;
    float2 o0, o1, o2;
    o0.x = c0x;
    o0.y = c0y;
    o1.x = W13 * c0x + W23 * c1x;
    o1.y = W13 * c0y + W23 * c1y;
    o2.x = W23 * c1x + W13 * c2x;
    o2.y = W23 * c1y + W13 * c2y;

    float2* orow = out + (((size_t)b * OD + z) * OH + y) * OW + 3 * t;
    orow[0] = o0;
    orow[1] = o1;
    orow[2] = o2;
}

extern "C" void kernel_launch(void* const* d_in, const int* in_sizes, int n_in,
                              void* d_out, int out_size, void* d_ws, size_t ws_size,
                              hipStream_t stream) {
    const float2* in = (const float2*)d_in[0];
    float2* out = (float2*)d_out;
    dim3 block(64, 4, 1);
    dim3 grid(OH / 4, OD, B);
    resize_trilinear3<<<grid, block, 0, stream>>>(in, out);
}